// Round 1
// baseline (489.830 us; speedup 1.0000x reference)
//
#include <hip/hip_runtime.h>
#include <math.h>

#define D_FEAT    2048
#define N_MEM     200000
#define N_CLASSES 1000
#define NC4       (N_CLASSES / 4)   // 250 float4 per V row
#define THETA     5.0f
#define BLK       256

// One block handles BLK consecutive memory slots (columns of K / rows of V).
// Phase A: per-thread dot product over D_FEAT (coalesced across j).
// Phase B: block-wide sims @ V partial, float4 per thread, atomicAdd to acc.
__global__ __launch_bounds__(BLK) void cache_fused_kernel(
    const float* __restrict__ x,   // [D_FEAT]
    const float* __restrict__ K,   // [D_FEAT][N_MEM]
    const float* __restrict__ V,   // [N_MEM][N_CLASSES]
    float*       __restrict__ acc) // [N_CLASSES], pre-zeroed; atomic accumulate
{
    __shared__ float x_lds[D_FEAT];
    __shared__ float sims[BLK];
    __shared__ float wred[BLK / 64];

    const int t = threadIdx.x;

    // ---- stage x into LDS, compute sum of squares for the global L2 norm ----
    float ss = 0.f;
    #pragma unroll
    for (int k = 0; k < D_FEAT / BLK; ++k) {
        float v = x[t + k * BLK];
        x_lds[t + k * BLK] = v;
        ss += v * v;
    }
    // wave(64) butterfly reduce
    #pragma unroll
    for (int off = 32; off >= 1; off >>= 1)
        ss += __shfl_xor(ss, off, 64);
    if ((t & 63) == 0) wred[t >> 6] = ss;
    __syncthreads();   // covers x_lds staging + wred
    const float scale = THETA / sqrtf(wred[0] + wred[1] + wred[2] + wred[3]);

    // ---- Phase A: dot(x, K[:, j]) for j = j0 + t ----
    const int j0 = blockIdx.x * BLK;
    const int j  = j0 + t;
    float dot = 0.f;
    if (j < N_MEM) {
        const float* kp = K + j;
        float a0 = 0.f, a1 = 0.f, a2 = 0.f, a3 = 0.f;
        for (int d = 0; d < D_FEAT; d += 4) {
            a0 = fmaf(x_lds[d + 0], kp[(size_t)(d + 0) * N_MEM], a0);
            a1 = fmaf(x_lds[d + 1], kp[(size_t)(d + 1) * N_MEM], a1);
            a2 = fmaf(x_lds[d + 2], kp[(size_t)(d + 2) * N_MEM], a2);
            a3 = fmaf(x_lds[d + 3], kp[(size_t)(d + 3) * N_MEM], a3);
        }
        dot = (a0 + a1) + (a2 + a3);
        sims[t] = expf(scale * dot);
    }
    __syncthreads();

    // ---- Phase B: partial p[c] = sum_j sims[j] * V[j][c], float4 classes ----
    const int jcnt = min(BLK, N_MEM - j0);
    if (t < NC4) {
        float4 a = make_float4(0.f, 0.f, 0.f, 0.f);
        const float4* Vp = (const float4*)V + (size_t)j0 * NC4 + t;
        for (int jj = 0; jj < jcnt; ++jj) {
            const float  s  = sims[jj];
            const float4 vv = Vp[(size_t)jj * NC4];
            a.x = fmaf(s, vv.x, a.x);
            a.y = fmaf(s, vv.y, a.y);
            a.z = fmaf(s, vv.z, a.z);
            a.w = fmaf(s, vv.w, a.w);
        }
        atomicAdd(&acc[t * 4 + 0], a.x);
        atomicAdd(&acc[t * 4 + 1], a.y);
        atomicAdd(&acc[t * 4 + 2], a.z);
        atomicAdd(&acc[t * 4 + 3], a.w);
    }
}

__global__ void log_inplace_kernel(float* __restrict__ out)
{
    const int c = blockIdx.x * blockDim.x + threadIdx.x;
    if (c < N_CLASSES) out[c] = logf(out[c]);
}

extern "C" void kernel_launch(void* const* d_in, const int* in_sizes, int n_in,
                              void* d_out, int out_size, void* d_ws, size_t ws_size,
                              hipStream_t stream)
{
    const float* x = (const float*)d_in[0];   // [1, 2048]
    const float* K = (const float*)d_in[1];   // [2048, 200000]
    const float* V = (const float*)d_in[2];   // [200000, 1000]
    float* out = (float*)d_out;               // [1, 1000]

    // zero the accumulator each call (harness poisons d_out once, never re-poisons)
    hipMemsetAsync(out, 0, N_CLASSES * sizeof(float), stream);

    const int grid = (N_MEM + BLK - 1) / BLK;  // 782 blocks
    cache_fused_kernel<<<grid, BLK, 0, stream>>>(x, K, V, out);
    log_inplace_kernel<<<(N_CLASSES + 255) / 256, 256, 0, stream>>>(out);
}

// Round 2
// 480.039 us; speedup vs baseline: 1.0204x; 1.0204x over previous
//
#include <hip/hip_runtime.h>
#include <math.h>

#define D_FEAT    2048
#define N_MEM     200000
#define N_CLASSES 1000
#define NC4       (N_CLASSES / 4)   // 250 float4 per V row
#define THETA     5.0f
#define BLK       256
#define COLS      256               // memory columns per block
#define DCHUNK    (D_FEAT / 4)      // 512 rows of K per wave
#define NM4       (N_MEM / 4)       // K row stride in float4

// One block handles COLS consecutive memory slots.
// Phase A: 16B/lane K loads — lane tx owns 4 consecutive columns (float4),
//          wave ty owns D-chunk [ty*512, ty*512+512); partials reduced in LDS.
// Phase B: block-wide sims @ V partial, float4 per thread, atomicAdd to acc.
__global__ __launch_bounds__(BLK) void cache_fused_kernel(
    const float* __restrict__ x,   // [D_FEAT]
    const float* __restrict__ K,   // [D_FEAT][N_MEM]
    const float* __restrict__ V,   // [N_MEM][N_CLASSES]
    float*       __restrict__ acc) // [N_CLASSES], zeroed; atomic accumulate
{
    __shared__ float  x_lds[D_FEAT];
    __shared__ float4 partl[4][64];
    __shared__ float  sims[COLS];
    __shared__ float  wred[BLK / 64];

    const int t = threadIdx.x;

    // ---- stage x (float4) into LDS + sum of squares for global L2 norm ----
    float ss = 0.f;
    const float4* x4 = (const float4*)x;
    #pragma unroll
    for (int k = 0; k < D_FEAT / 4 / BLK; ++k) {   // 2 iterations
        float4 v = x4[t + k * BLK];
        ((float4*)x_lds)[t + k * BLK] = v;
        ss += v.x * v.x + v.y * v.y + v.z * v.z + v.w * v.w;
    }
    #pragma unroll
    for (int off = 32; off >= 1; off >>= 1)
        ss += __shfl_xor(ss, off, 64);
    if ((t & 63) == 0) wred[t >> 6] = ss;
    __syncthreads();   // covers x_lds staging + wred
    const float scale = THETA / sqrtf(wred[0] + wred[1] + wred[2] + wred[3]);

    // ---- Phase A: dot(x, K[:, j]) for 4 columns per lane, D split 4 ways ----
    const int tx = t & 63;          // column-quad index
    const int ty = t >> 6;          // D-chunk index (wave id)
    const int j0 = (int)blockIdx.x * COLS;
    const int jq = j0 + tx * 4;     // first of this lane's 4 columns
    float4 a = make_float4(0.f, 0.f, 0.f, 0.f);
    if (jq < N_MEM) {               // N_MEM % 4 == 0 -> whole quad valid
        const float4* kp = (const float4*)(K + (size_t)ty * DCHUNK * N_MEM + jq);
        const float*  xp = x_lds + ty * DCHUNK;
        #pragma unroll 8
        for (int dd = 0; dd < DCHUNK; ++dd) {
            const float  xv = xp[dd];                  // LDS broadcast (free)
            const float4 kv = kp[(size_t)dd * NM4];    // 16B/lane, coalesced
            a.x = fmaf(xv, kv.x, a.x);
            a.y = fmaf(xv, kv.y, a.y);
            a.z = fmaf(xv, kv.z, a.z);
            a.w = fmaf(xv, kv.w, a.w);
        }
    }
    partl[ty][tx] = a;
    __syncthreads();

    if (t < 64) {
        const float4 s0 = partl[0][t], s1 = partl[1][t];
        const float4 s2 = partl[2][t], s3 = partl[3][t];
        sims[t * 4 + 0] = expf(scale * ((s0.x + s1.x) + (s2.x + s3.x)));
        sims[t * 4 + 1] = expf(scale * ((s0.y + s1.y) + (s2.y + s3.y)));
        sims[t * 4 + 2] = expf(scale * ((s0.z + s1.z) + (s2.z + s3.z)));
        sims[t * 4 + 3] = expf(scale * ((s0.w + s1.w) + (s2.w + s3.w)));
    }
    __syncthreads();

    // ---- Phase B: partial p[c] = sum_j sims[j] * V[j][c], float4 classes ----
    const int jcnt = min(COLS, N_MEM - j0);
    if (t < NC4) {
        float4 a4 = make_float4(0.f, 0.f, 0.f, 0.f);
        const float4* Vp = (const float4*)V + (size_t)j0 * NC4 + t;
        for (int jj = 0; jj < jcnt; ++jj) {
            const float  s  = sims[jj];
            const float4 vv = Vp[(size_t)jj * NC4];
            a4.x = fmaf(s, vv.x, a4.x);
            a4.y = fmaf(s, vv.y, a4.y);
            a4.z = fmaf(s, vv.z, a4.z);
            a4.w = fmaf(s, vv.w, a4.w);
        }
        atomicAdd(&acc[t * 4 + 0], a4.x);
        atomicAdd(&acc[t * 4 + 1], a4.y);
        atomicAdd(&acc[t * 4 + 2], a4.z);
        atomicAdd(&acc[t * 4 + 3], a4.w);
    }
}

__global__ void log_inplace_kernel(float* __restrict__ out)
{
    const int c = blockIdx.x * blockDim.x + threadIdx.x;
    if (c < N_CLASSES) out[c] = logf(out[c]);
}

extern "C" void kernel_launch(void* const* d_in, const int* in_sizes, int n_in,
                              void* d_out, int out_size, void* d_ws, size_t ws_size,
                              hipStream_t stream)
{
    const float* x = (const float*)d_in[0];   // [1, 2048]
    const float* K = (const float*)d_in[1];   // [2048, 200000]
    const float* V = (const float*)d_in[2];   // [200000, 1000]
    float* out = (float*)d_out;               // [1, 1000]

    // zero the accumulator each call (harness poisons d_out once, never re-poisons)
    hipMemsetAsync(out, 0, N_CLASSES * sizeof(float), stream);

    const int grid = (N_MEM + COLS - 1) / COLS;  // 782 blocks
    cache_fused_kernel<<<grid, BLK, 0, stream>>>(x, K, V, out);
    log_inplace_kernel<<<(N_CLASSES + 255) / 256, 256, 0, stream>>>(out);
}

// Round 3
// 474.625 us; speedup vs baseline: 1.0320x; 1.0114x over previous
//
#include <hip/hip_runtime.h>
#include <math.h>

#define D_FEAT    2048
#define N_MEM     200000
#define N_CLASSES 1000
#define NC4       (N_CLASSES / 4)   // 250 float4 per V row
#define THETA     5.0f
#define BLK       256
#define GRID      768               // 3 blocks per CU exactly (256 CUs)
#define NQ_TOT    (N_MEM / 4)       // 50000 column-quads
#define QBASE     (NQ_TOT / GRID)   // 65 quads per block
#define QREM      (NQ_TOT - QBASE * GRID)  // 80 blocks get one extra quad
#define DCHUNK    (D_FEAT / 4)      // 512 K-rows per wave
#define NM4       (N_MEM / 4)       // K row stride in float4
#define MAXQ      (QBASE + 1)       // 66

// Balanced: block b owns quads [qstart, qstart+nq), nq in {65,66}.
// Phase A: lane tx handles quad qi = p*64+tx (p=0,1); wave ty owns D-chunk
//          [ty*512, ty*512+512); 16B/lane coalesced K loads; LDS reduce.
// Phase B: block's sims @ V rows, float4 per thread, atomicAdd into acc.
__global__ __launch_bounds__(BLK) void cache_fused_kernel(
    const float* __restrict__ x,   // [D_FEAT]
    const float* __restrict__ K,   // [D_FEAT][N_MEM]
    const float* __restrict__ V,   // [N_MEM][N_CLASSES]
    float*       __restrict__ acc) // [N_CLASSES], zeroed; atomic accumulate
{
    __shared__ float  x_lds[D_FEAT];
    __shared__ float4 partl[4][MAXQ];
    __shared__ float  sims[MAXQ * 4];
    __shared__ float  wred[BLK / 64];

    const int t = threadIdx.x;
    const int b = blockIdx.x;

    // ---- stage x (float4) into LDS + sum of squares for global L2 norm ----
    float ss = 0.f;
    const float4* x4 = (const float4*)x;
    #pragma unroll
    for (int k = 0; k < D_FEAT / 4 / BLK; ++k) {   // 2 iterations
        float4 v = x4[t + k * BLK];
        ((float4*)x_lds)[t + k * BLK] = v;
        ss += v.x * v.x + v.y * v.y + v.z * v.z + v.w * v.w;
    }
    #pragma unroll
    for (int off = 32; off >= 1; off >>= 1)
        ss += __shfl_xor(ss, off, 64);
    if ((t & 63) == 0) wred[t >> 6] = ss;
    __syncthreads();   // covers x_lds staging + wred
    const float scale = THETA / sqrtf(wred[0] + wred[1] + wred[2] + wred[3]);

    // ---- balanced work assignment ----
    const int qstart = QBASE * b + (b < QREM ? b : QREM);
    const int nq     = QBASE + (b < QREM ? 1 : 0);      // 65 or 66
    const int cstart = qstart * 4;
    const int ncols  = nq * 4;                          // 260 or 264

    // ---- Phase A: dot(x, K[:, j]) for 4 columns per lane, D split 4 ways ----
    const int tx = t & 63;          // lane within wave -> quad index
    const int ty = t >> 6;          // wave id -> D-chunk
    const float* xp = x_lds + ty * DCHUNK;
    const float* kbase = K + (size_t)ty * DCHUNK * N_MEM;
    #pragma unroll
    for (int p = 0; p < 2; ++p) {
        const int qi = p * 64 + tx;
        if (qi < nq) {
            const int j = (qstart + qi) * 4;
            const float4* kp = (const float4*)(kbase + j);
            float4 a = make_float4(0.f, 0.f, 0.f, 0.f);
            #pragma unroll 8
            for (int dd = 0; dd < DCHUNK; ++dd) {
                const float  xv = xp[dd];                  // LDS broadcast
                const float4 kv = kp[(size_t)dd * NM4];    // 16B/lane coalesced
                a.x = fmaf(xv, kv.x, a.x);
                a.y = fmaf(xv, kv.y, a.y);
                a.z = fmaf(xv, kv.z, a.z);
                a.w = fmaf(xv, kv.w, a.w);
            }
            partl[ty][qi] = a;
        }
    }
    __syncthreads();

    if (t < nq) {
        const float4 s0 = partl[0][t], s1 = partl[1][t];
        const float4 s2 = partl[2][t], s3 = partl[3][t];
        sims[t * 4 + 0] = expf(scale * ((s0.x + s1.x) + (s2.x + s3.x)));
        sims[t * 4 + 1] = expf(scale * ((s0.y + s1.y) + (s2.y + s3.y)));
        sims[t * 4 + 2] = expf(scale * ((s0.z + s1.z) + (s2.z + s3.z)));
        sims[t * 4 + 3] = expf(scale * ((s0.w + s1.w) + (s2.w + s3.w)));
    }
    __syncthreads();

    // ---- Phase B: partial p[c] = sum_j sims[j] * V[j][c], float4 classes ----
    if (t < NC4) {
        float4 a4 = make_float4(0.f, 0.f, 0.f, 0.f);
        const float4* Vp = (const float4*)V + (size_t)cstart * NC4 + t;
        for (int jj = 0; jj < ncols; ++jj) {
            const float  s  = sims[jj];
            const float4 vv = Vp[(size_t)jj * NC4];
            a4.x = fmaf(s, vv.x, a4.x);
            a4.y = fmaf(s, vv.y, a4.y);
            a4.z = fmaf(s, vv.z, a4.z);
            a4.w = fmaf(s, vv.w, a4.w);
        }
        atomicAdd(&acc[t * 4 + 0], a4.x);
        atomicAdd(&acc[t * 4 + 1], a4.y);
        atomicAdd(&acc[t * 4 + 2], a4.z);
        atomicAdd(&acc[t * 4 + 3], a4.w);
    }
}

__global__ void log_inplace_kernel(float* __restrict__ out)
{
    const int c = blockIdx.x * blockDim.x + threadIdx.x;
    if (c < N_CLASSES) out[c] = logf(out[c]);
}

extern "C" void kernel_launch(void* const* d_in, const int* in_sizes, int n_in,
                              void* d_out, int out_size, void* d_ws, size_t ws_size,
                              hipStream_t stream)
{
    const float* x = (const float*)d_in[0];   // [1, 2048]
    const float* K = (const float*)d_in[1];   // [2048, 200000]
    const float* V = (const float*)d_in[2];   // [200000, 1000]
    float* out = (float*)d_out;               // [1, 1000]

    // zero the accumulator each call (harness poisons d_out once, never re-poisons)
    hipMemsetAsync(out, 0, N_CLASSES * sizeof(float), stream);

    cache_fused_kernel<<<GRID, BLK, 0, stream>>>(x, K, V, out);
    log_inplace_kernel<<<(N_CLASSES + 255) / 256, 256, 0, stream>>>(out);
}

// Round 4
// 417.499 us; speedup vs baseline: 1.1732x; 1.1368x over previous
//
#include <hip/hip_runtime.h>
#include <math.h>

#define D_FEAT    2048
#define N_MEM     200000
#define N_CLASSES 1000
#define NC4       (N_CLASSES / 4)       // 250 float4 per V row
#define THETA     5.0f
#define BLK       256
#define GRID      768                   // 3 blocks per CU exactly
#define OCT_TOT   (N_MEM / 32)          // 6250 octets (8 quads = 128B of a K row)
#define OBASE     (OCT_TOT / GRID)      // 8 octets per block
#define OREM      (OCT_TOT - OBASE*GRID)// first 106 blocks take one extra octet
#define DCHUNK    (D_FEAT / 4)          // 512 K-rows per wave
#define NM4       (N_MEM / 4)           // K row stride in float4
#define MAXQ      ((OBASE + 1) * 8)     // 72 quads max per block

// Work unit: octet = 8 quads = 32 columns = 128 bytes of each K row.
// qstart is a multiple of 8 -> every K load is 128B-aligned, and the row
// stride 800000B is a multiple of 128 -> alignment holds for all rows.
template<bool USE_WS>
__global__ __launch_bounds__(BLK) void cache_fused_kernel(
    const float* __restrict__ x,     // [D_FEAT]
    const float* __restrict__ K,     // [D_FEAT][N_MEM]
    const float* __restrict__ V,     // [N_MEM][N_CLASSES]
    float*       __restrict__ outp)  // USE_WS: partials [GRID][N_CLASSES]; else acc[N_CLASSES]
{
    __shared__ float  x_lds[D_FEAT];
    __shared__ float4 partl[4][MAXQ];
    __shared__ float  sims[MAXQ * 4];
    __shared__ float  wred[BLK / 64];

    const int t = threadIdx.x;
    const int b = blockIdx.x;

    // ---- stage x (float4) into LDS + sum of squares for global L2 norm ----
    float ss = 0.f;
    const float4* x4 = (const float4*)x;
    #pragma unroll
    for (int k = 0; k < D_FEAT / 4 / BLK; ++k) {   // 2 iterations
        float4 v = x4[t + k * BLK];
        ((float4*)x_lds)[t + k * BLK] = v;
        ss += v.x * v.x + v.y * v.y + v.z * v.z + v.w * v.w;
    }
    #pragma unroll
    for (int off = 32; off >= 1; off >>= 1)
        ss += __shfl_xor(ss, off, 64);
    if ((t & 63) == 0) wred[t >> 6] = ss;
    __syncthreads();   // covers x_lds staging + wred
    const float scale = THETA / sqrtf(wred[0] + wred[1] + wred[2] + wred[3]);

    // ---- balanced, 128B-aligned work assignment ----
    const int ostart = OBASE * b + (b < OREM ? b : OREM);
    const int noct   = OBASE + (b < OREM ? 1 : 0);     // 8 or 9
    const int qstart = ostart * 8;                     // multiple of 8
    const int nq     = noct * 8;                       // 64 or 72
    const int ncols  = nq * 4;                         // 256 or 288

    // ---- Phase A: dot(x, K[:, j]); lane = quad, wave = D-chunk ----
    const int tx = t & 63;
    const int ty = t >> 6;
    const float*  xp = x_lds + ty * DCHUNK;
    const float4* kb = (const float4*)K + (size_t)ty * DCHUNK * NM4 + qstart;
    #pragma unroll
    for (int p = 0; p < 2; ++p) {
        const int qi = p * 64 + tx;
        if (qi < nq) {
            const float4* kp = kb + qi;
            float4 a = make_float4(0.f, 0.f, 0.f, 0.f);
            #pragma unroll 16
            for (int dd = 0; dd < DCHUNK; ++dd) {
                const float  xv = xp[dd];                  // LDS broadcast
                const float4 kv = kp[(size_t)dd * NM4];    // 16B/lane, 128B-aligned wave req
                a.x = fmaf(xv, kv.x, a.x);
                a.y = fmaf(xv, kv.y, a.y);
                a.z = fmaf(xv, kv.z, a.z);
                a.w = fmaf(xv, kv.w, a.w);
            }
            partl[ty][qi] = a;
        }
    }
    __syncthreads();

    if (t < nq) {
        const float4 s0 = partl[0][t], s1 = partl[1][t];
        const float4 s2 = partl[2][t], s3 = partl[3][t];
        sims[t * 4 + 0] = expf(scale * ((s0.x + s1.x) + (s2.x + s3.x)));
        sims[t * 4 + 1] = expf(scale * ((s0.y + s1.y) + (s2.y + s3.y)));
        sims[t * 4 + 2] = expf(scale * ((s0.z + s1.z) + (s2.z + s3.z)));
        sims[t * 4 + 3] = expf(scale * ((s0.w + s1.w) + (s2.w + s3.w)));
    }
    __syncthreads();

    // ---- Phase B: partial p[c] = sum_j sims[j] * V[j][c] ----
    if (t < NC4) {
        float4 a4 = make_float4(0.f, 0.f, 0.f, 0.f);
        const float4* Vp = (const float4*)V + (size_t)qstart * 4 * NC4 + t;
        #pragma unroll 4
        for (int jj = 0; jj < ncols; ++jj) {
            const float  s  = sims[jj];
            const float4 vv = Vp[(size_t)jj * NC4];
            a4.x = fmaf(s, vv.x, a4.x);
            a4.y = fmaf(s, vv.y, a4.y);
            a4.z = fmaf(s, vv.z, a4.z);
            a4.w = fmaf(s, vv.w, a4.w);
        }
        if (USE_WS) {
            ((float4*)outp)[(size_t)b * NC4 + t] = a4;   // per-block partials
        } else {
            atomicAdd(&outp[t * 4 + 0], a4.x);
            atomicAdd(&outp[t * 4 + 1], a4.y);
            atomicAdd(&outp[t * 4 + 2], a4.z);
            atomicAdd(&outp[t * 4 + 3], a4.w);
        }
    }
}

// One wave per class-quad: sum GRID partials, write log. Deterministic order.
__global__ __launch_bounds__(64) void reduce_log_kernel(
    const float* __restrict__ ws, float* __restrict__ out)
{
    const int cq = blockIdx.x;     // 0..NC4-1
    const int l  = threadIdx.x;    // 0..63
    float4 s = make_float4(0.f, 0.f, 0.f, 0.f);
    #pragma unroll
    for (int b = l; b < GRID; b += 64) {   // 12 iterations
        const float4 v = ((const float4*)ws)[(size_t)b * NC4 + cq];
        s.x += v.x; s.y += v.y; s.z += v.z; s.w += v.w;
    }
    #pragma unroll
    for (int off = 32; off >= 1; off >>= 1) {
        s.x += __shfl_xor(s.x, off, 64);
        s.y += __shfl_xor(s.y, off, 64);
        s.z += __shfl_xor(s.z, off, 64);
        s.w += __shfl_xor(s.w, off, 64);
    }
    if (l == 0) {
        out[cq * 4 + 0] = logf(s.x);
        out[cq * 4 + 1] = logf(s.y);
        out[cq * 4 + 2] = logf(s.z);
        out[cq * 4 + 3] = logf(s.w);
    }
}

__global__ void log_inplace_kernel(float* __restrict__ out)
{
    const int c = blockIdx.x * blockDim.x + threadIdx.x;
    if (c < N_CLASSES) out[c] = logf(out[c]);
}

extern "C" void kernel_launch(void* const* d_in, const int* in_sizes, int n_in,
                              void* d_out, int out_size, void* d_ws, size_t ws_size,
                              hipStream_t stream)
{
    const float* x = (const float*)d_in[0];   // [1, 2048]
    const float* K = (const float*)d_in[1];   // [2048, 200000]
    const float* V = (const float*)d_in[2];   // [200000, 1000]
    float* out = (float*)d_out;               // [1, 1000]

    const size_t ws_need = (size_t)GRID * N_CLASSES * sizeof(float);  // 3.07 MB
    if (ws_size >= ws_need) {
        float* partials = (float*)d_ws;
        cache_fused_kernel<true><<<GRID, BLK, 0, stream>>>(x, K, V, partials);
        reduce_log_kernel<<<NC4, 64, 0, stream>>>(partials, out);
    } else {
        hipMemsetAsync(out, 0, N_CLASSES * sizeof(float), stream);
        cache_fused_kernel<false><<<GRID, BLK, 0, stream>>>(x, K, V, out);
        log_inplace_kernel<<<(N_CLASSES + 255) / 256, 256, 0, stream>>>(out);
    }
}